// Round 1
// baseline (2721.751 us; speedup 1.0000x reference)
//
#include <hip/hip_runtime.h>
#include <hip/hip_bf16.h>

#define H 2048
#define FDIM 1408
#define NE 64
#define CAP 512
#define NTOK 2048
#define FSH 2816

typedef float  f32x4  __attribute__((ext_vector_type(4)));
typedef short  s16x8  __attribute__((ext_vector_type(8)));
typedef unsigned short u16;
typedef u16    u16x4v __attribute__((ext_vector_type(4)));

__device__ __forceinline__ u16 f2bf(float f) {
    union { float f; unsigned u; } v; v.f = f;
    unsigned u = v.u;
    u += 0x7fffu + ((u >> 16) & 1u);
    return (u16)(u >> 16);
}
__device__ __forceinline__ float bf2f(u16 b) {
    union { unsigned u; float f; } v; v.u = ((unsigned)b) << 16;
    return v.f;
}
// element-granular XOR swizzle (multiples of 8 elems = 16B) within 64-elem rows
__device__ __forceinline__ int swze(int row) {
    return (((row & 7) ^ ((row >> 3) & 7)) << 3);
}
__device__ __forceinline__ void wr4(u16* dst, float a, float b, float c, float d) {
    u16x4v v; v[0] = f2bf(a); v[1] = f2bf(b); v[2] = f2bf(c); v[3] = f2bf(d);
    *(u16x4v*)dst = v;
}

// ---------------- init: zero per-expert counters ----------------
__global__ void init_cnt(int* __restrict__ c) { c[threadIdx.x] = 0; }

// ---------------- gate: logits -> softmax -> top6 -> slot assign ----------------
__global__ __launch_bounds__(64) void gate_topk(
    const float* __restrict__ xg, const float* __restrict__ gw,
    int* __restrict__ cnt, int* __restrict__ tok_of,
    int* __restrict__ slot_enc, float* __restrict__ tw)
{
    const int t = blockIdx.x;
    const int lane = threadIdx.x;              // 64 threads = 1 wave
    __shared__ float4 xs[512];
    const float4* xr = (const float4*)(xg + (size_t)t * H);
    #pragma unroll
    for (int i = 0; i < 8; ++i) xs[i * 64 + lane] = xr[i * 64 + lane];
    __syncthreads();

    const float4* gr = (const float4*)(gw + (size_t)lane * H);
    float acc = 0.f;
    #pragma unroll 4
    for (int i = 0; i < 512; ++i) {
        float4 a = xs[i], b = gr[i];
        acc += a.x * b.x + a.y * b.y + a.z * b.z + a.w * b.w;
    }
    // softmax over 64 experts (one per lane)
    float m = acc;
    #pragma unroll
    for (int off = 32; off; off >>= 1) m = fmaxf(m, __shfl_xor(m, off));
    float p = __expf(acc - m);
    float s = p;
    #pragma unroll
    for (int off = 32; off; off >>= 1) s += __shfl_xor(s, off);
    p = p / s;

    // iterative top-6 (ties -> lower index, matches lax.top_k)
    float myw = 0.f; int mye = 0;
    float v = p;
    for (int k = 0; k < 6; ++k) {
        float bv = v; int bi = lane;
        #pragma unroll
        for (int off = 32; off; off >>= 1) {
            float ov = __shfl_xor(bv, off);
            int   oi = __shfl_xor(bi, off);
            if (ov > bv || (ov == bv && oi < bi)) { bv = ov; bi = oi; }
        }
        if (lane == k)  { myw = bv; mye = bi; }
        if (lane == bi) v = -1.f;
    }
    if (lane < 6) {
        int slot = atomicAdd(&cnt[mye], 1);
        int enc = -1;
        if (slot < CAP) { tok_of[mye * CAP + slot] = t; enc = mye * CAP + slot; }
        slot_enc[t * 6 + lane] = enc;
        tw[t * 6 + lane] = myw;               // SCALE == 1.0
    }
}

// ---------------- fused gate+up grouped GEMM + SiLU ----------------
// ROUTED: A = gathered x rows (fp32), B = w_gate/w_up [H][F] (transpose-staged)
// !ROUTED: A = x rows directly,      B = sh_gate/sh_up [FSH][H] (direct-staged)
// act output is bf16 with the LDS read-swizzle pre-baked into the f coordinate.
template<bool ROUTED>
__global__ __launch_bounds__(256) void dual_gemm(
    const float* __restrict__ x, const int* __restrict__ tok_of,
    const int* __restrict__ cnt_arr, const float* __restrict__ wg,
    const float* __restrict__ wu, u16* __restrict__ act, int Fd)
{
    __shared__ u16 As[256 * 64];
    __shared__ u16 Bgs[64 * 64];
    __shared__ u16 Bus[64 * 64];

    const int e = blockIdx.z;
    int cnt;
    if constexpr (ROUTED) { cnt = cnt_arr[e]; cnt = cnt < CAP ? cnt : CAP; }
    else cnt = NTOK;
    const int m0 = blockIdx.y * 256;
    if (m0 >= cnt) return;
    const int f0 = blockIdx.x * 64;

    const float* wg_e = wg;
    const float* wu_e = wu;
    u16* act_e = act;
    const int* tok = nullptr;
    if constexpr (ROUTED) {
        wg_e += (size_t)e * H * Fd;
        wu_e += (size_t)e * H * Fd;
        act_e += (size_t)e * CAP * Fd;
        tok = tok_of + e * CAP;
    }

    const int tid = threadIdx.x;
    const int lane = tid & 63;
    const int wv = tid >> 6;

    f32x4 accg[4][4], accu[4][4];
    const f32x4 zero4 = {0.f, 0.f, 0.f, 0.f};
    #pragma unroll
    for (int i = 0; i < 4; ++i)
        #pragma unroll
        for (int j = 0; j < 4; ++j) { accg[i][j] = zero4; accu[i][j] = zero4; }

    for (int kt = 0; kt < H / 64; ++kt) {
        // ---- stage A: 256 rows x 64 k, fp32 -> bf16, swizzled ----
        #pragma unroll
        for (int it = 0; it < 16; ++it) {
            int chunk = it * 256 + tid;
            int row = chunk >> 4, c4 = chunk & 15;
            int srow = m0 + row;
            int tkn;
            if constexpr (ROUTED) tkn = (srow < cnt) ? tok[srow] : 0;
            else tkn = srow;
            const float4 v = *(const float4*)(x + (size_t)tkn * H + kt * 64 + c4 * 4);
            wr4(&As[row * 64 + ((c4 * 4) ^ swze(row))], v.x, v.y, v.z, v.w);
        }
        // ---- stage B (gate & up) ----
        if constexpr (ROUTED) {
            int n4 = tid & 15, k4 = tid >> 4;
            const float* s0 = wg_e + (size_t)(kt * 64 + k4 * 4) * Fd + f0 + n4 * 4;
            {
                float4 r0 = *(const float4*)(s0);
                float4 r1 = *(const float4*)(s0 + (size_t)Fd);
                float4 r2 = *(const float4*)(s0 + 2 * (size_t)Fd);
                float4 r3 = *(const float4*)(s0 + 3 * (size_t)Fd);
                wr4(&Bgs[(n4*4+0)*64 + ((k4*4) ^ swze(n4*4+0))], r0.x, r1.x, r2.x, r3.x);
                wr4(&Bgs[(n4*4+1)*64 + ((k4*4) ^ swze(n4*4+1))], r0.y, r1.y, r2.y, r3.y);
                wr4(&Bgs[(n4*4+2)*64 + ((k4*4) ^ swze(n4*4+2))], r0.z, r1.z, r2.z, r3.z);
                wr4(&Bgs[(n4*4+3)*64 + ((k4*4) ^ swze(n4*4+3))], r0.w, r1.w, r2.w, r3.w);
            }
            const float* s1 = wu_e + (size_t)(kt * 64 + k4 * 4) * Fd + f0 + n4 * 4;
            {
                float4 r0 = *(const float4*)(s1);
                float4 r1 = *(const float4*)(s1 + (size_t)Fd);
                float4 r2 = *(const float4*)(s1 + 2 * (size_t)Fd);
                float4 r3 = *(const float4*)(s1 + 3 * (size_t)Fd);
                wr4(&Bus[(n4*4+0)*64 + ((k4*4) ^ swze(n4*4+0))], r0.x, r1.x, r2.x, r3.x);
                wr4(&Bus[(n4*4+1)*64 + ((k4*4) ^ swze(n4*4+1))], r0.y, r1.y, r2.y, r3.y);
                wr4(&Bus[(n4*4+2)*64 + ((k4*4) ^ swze(n4*4+2))], r0.z, r1.z, r2.z, r3.z);
                wr4(&Bus[(n4*4+3)*64 + ((k4*4) ^ swze(n4*4+3))], r0.w, r1.w, r2.w, r3.w);
            }
        } else {
            #pragma unroll
            for (int it = 0; it < 4; ++it) {
                int chunk = it * 256 + tid;
                int row = chunk >> 4, c4 = chunk & 15;
                const float4 v = *(const float4*)(wg_e + (size_t)(f0 + row) * H + kt * 64 + c4 * 4);
                wr4(&Bgs[row * 64 + ((c4 * 4) ^ swze(row))], v.x, v.y, v.z, v.w);
                const float4 v2 = *(const float4*)(wu_e + (size_t)(f0 + row) * H + kt * 64 + c4 * 4);
                wr4(&Bus[row * 64 + ((c4 * 4) ^ swze(row))], v2.x, v2.y, v2.z, v2.w);
            }
        }
        __syncthreads();
        // ---- compute: 2 x (4 A-frags x 4 B-frags x 2 mats) MFMAs ----
        #pragma unroll
        for (int kk = 0; kk < 2; ++kk) {
            int ko = kk * 32 + (lane >> 4) * 8;
            s16x8 a[4], bg[4], bu[4];
            #pragma unroll
            for (int mi = 0; mi < 4; ++mi) {
                int r = wv * 64 + mi * 16 + (lane & 15);
                a[mi] = *(const s16x8*)&As[r * 64 + (ko ^ swze(r))];
            }
            #pragma unroll
            for (int ni = 0; ni < 4; ++ni) {
                int r = ni * 16 + (lane & 15);
                bg[ni] = *(const s16x8*)&Bgs[r * 64 + (ko ^ swze(r))];
                bu[ni] = *(const s16x8*)&Bus[r * 64 + (ko ^ swze(r))];
            }
            #pragma unroll
            for (int mi = 0; mi < 4; ++mi)
                #pragma unroll
                for (int ni = 0; ni < 4; ++ni) {
                    accg[mi][ni] = __builtin_amdgcn_mfma_f32_16x16x32_bf16(a[mi], bg[ni], accg[mi][ni], 0, 0, 0);
                    accu[mi][ni] = __builtin_amdgcn_mfma_f32_16x16x32_bf16(a[mi], bu[ni], accu[mi][ni], 0, 0, 0);
                }
        }
        __syncthreads();
    }
    // ---- epilogue: silu(g)*u -> bf16 act (swizzle baked into f) ----
    #pragma unroll
    for (int mi = 0; mi < 4; ++mi)
        #pragma unroll
        for (int ni = 0; ni < 4; ++ni)
            #pragma unroll
            for (int r = 0; r < 4; ++r) {
                int srow = m0 + wv * 64 + mi * 16 + (lane >> 4) * 4 + r;
                if (srow < cnt) {
                    int fc = f0 + ni * 16 + (lane & 15);
                    float g = accg[mi][ni][r], u = accu[mi][ni][r];
                    float aa = (g / (1.f + __expf(-g))) * u;
                    int fs = fc ^ swze(srow);
                    act_e[(size_t)srow * Fd + fs] = f2bf(aa);
                }
            }
}

// ---------------- down-proj grouped GEMM ----------------
// ROUTED: A = act bf16 (pre-swizzled), B = w_down [F][H] transpose-staged, out = d bf16
// !ROUTED: A = act_sh bf16,            B = sh_down [H][FSH] direct-staged,  out = y fp32
template<bool ROUTED>
__global__ __launch_bounds__(256) void down_gemm(
    const u16* __restrict__ actA, const float* __restrict__ wdn,
    void* __restrict__ outp, const int* __restrict__ cnt_arr, int Kd)
{
    __shared__ u16 As[256 * 64];
    __shared__ u16 Bs[128 * 64];

    const int e = blockIdx.z;
    int cnt;
    if constexpr (ROUTED) { cnt = cnt_arr[e]; cnt = cnt < CAP ? cnt : CAP; }
    else cnt = NTOK;
    const int m0 = blockIdx.y * 256;
    if (m0 >= cnt) return;
    const int n0 = blockIdx.x * 128;

    const u16* A_e = actA;
    const float* B_e = wdn;
    if constexpr (ROUTED) {
        A_e += (size_t)e * CAP * Kd;
        B_e += (size_t)e * Kd * H;
    }

    const int tid = threadIdx.x, lane = tid & 63, wv = tid >> 6;
    const int wm = wv >> 1, wn = wv & 1;

    f32x4 acc[8][4];
    const f32x4 zero4 = {0.f, 0.f, 0.f, 0.f};
    #pragma unroll
    for (int i = 0; i < 8; ++i)
        #pragma unroll
        for (int j = 0; j < 4; ++j) acc[i][j] = zero4;

    for (int kt = 0; kt < Kd / 64; ++kt) {
        // ---- stage A: bf16 rows, linear copy (swizzle pre-baked) ----
        #pragma unroll
        for (int it = 0; it < 8; ++it) {
            int chunk = it * 256 + tid;
            int row = chunk >> 3, c = chunk & 7;
            s16x8 v = *(const s16x8*)(A_e + (size_t)(m0 + row) * Kd + kt * 64 + c * 8);
            *(s16x8*)&As[row * 64 + c * 8] = v;
        }
        // ---- stage B ----
        if constexpr (ROUTED) {
            int n4 = tid & 31;
            #pragma unroll
            for (int half = 0; half < 2; ++half) {
                int k4 = (tid >> 5) + half * 8;
                const float* s0 = B_e + (size_t)(kt * 64 + k4 * 4) * H + n0 + n4 * 4;
                float4 r0 = *(const float4*)(s0);
                float4 r1 = *(const float4*)(s0 + H);
                float4 r2 = *(const float4*)(s0 + 2 * H);
                float4 r3 = *(const float4*)(s0 + 3 * H);
                wr4(&Bs[(n4*4+0)*64 + ((k4*4) ^ swze(n4*4+0))], r0.x, r1.x, r2.x, r3.x);
                wr4(&Bs[(n4*4+1)*64 + ((k4*4) ^ swze(n4*4+1))], r0.y, r1.y, r2.y, r3.y);
                wr4(&Bs[(n4*4+2)*64 + ((k4*4) ^ swze(n4*4+2))], r0.z, r1.z, r2.z, r3.z);
                wr4(&Bs[(n4*4+3)*64 + ((k4*4) ^ swze(n4*4+3))], r0.w, r1.w, r2.w, r3.w);
            }
        } else {
            #pragma unroll
            for (int it = 0; it < 8; ++it) {
                int chunk = it * 256 + tid;
                int row = chunk >> 4, c4 = chunk & 15;
                const float4 v = *(const float4*)(B_e + (size_t)(n0 + row) * FSH + kt * 64 + c4 * 4);
                wr4(&Bs[row * 64 + ((c4 * 4) ^ swze(row))], v.x, v.y, v.z, v.w);
            }
        }
        __syncthreads();
        // ---- compute: 2 x (8 A-frags x 4 B-frags) MFMAs ----
        #pragma unroll
        for (int kk = 0; kk < 2; ++kk) {
            int ko = kk * 32 + (lane >> 4) * 8;
            s16x8 a[8], b[4];
            #pragma unroll
            for (int mi = 0; mi < 8; ++mi) {
                int r = wm * 128 + mi * 16 + (lane & 15);
                a[mi] = *(const s16x8*)&As[r * 64 + (ko ^ swze(r))];
            }
            #pragma unroll
            for (int ni = 0; ni < 4; ++ni) {
                int r = wn * 64 + ni * 16 + (lane & 15);
                b[ni] = *(const s16x8*)&Bs[r * 64 + (ko ^ swze(r))];
            }
            #pragma unroll
            for (int mi = 0; mi < 8; ++mi)
                #pragma unroll
                for (int ni = 0; ni < 4; ++ni)
                    acc[mi][ni] = __builtin_amdgcn_mfma_f32_16x16x32_bf16(a[mi], b[ni], acc[mi][ni], 0, 0, 0);
        }
        __syncthreads();
    }
    // ---- epilogue ----
    #pragma unroll
    for (int mi = 0; mi < 8; ++mi)
        #pragma unroll
        for (int ni = 0; ni < 4; ++ni)
            #pragma unroll
            for (int r = 0; r < 4; ++r) {
                int srow = m0 + wm * 128 + mi * 16 + (lane >> 4) * 4 + r;
                if (srow < cnt) {
                    int col = n0 + wn * 64 + ni * 16 + (lane & 15);
                    float vv = acc[mi][ni][r];
                    if constexpr (ROUTED)
                        ((u16*)outp)[(size_t)e * CAP * H + (size_t)srow * H + col] = f2bf(vv);
                    else
                        ((float*)outp)[(size_t)srow * H + col] = vv;
                }
            }
}

// ---------------- combine: y += sum_k w_k * d[enc_k] ----------------
__global__ __launch_bounds__(256) void combine(
    float* __restrict__ y, const u16* __restrict__ d,
    const int* __restrict__ slot_enc, const float* __restrict__ tw)
{
    const int t = blockIdx.x, tid = threadIdx.x;
    int enc[6]; float w[6];
    #pragma unroll
    for (int k = 0; k < 6; ++k) {
        enc[k] = slot_enc[t * 6 + k];
        w[k] = tw[t * 6 + k];
    }
    float4* yrow = (float4*)(y + (size_t)t * H);
    #pragma unroll
    for (int it = 0; it < 2; ++it) {
        int h4 = it * 256 + tid;
        float4 acc = yrow[h4];
        #pragma unroll
        for (int k = 0; k < 6; ++k) {
            if (enc[k] >= 0) {
                ushort4 dv = ((const ushort4*)(d + (size_t)enc[k] * H))[h4];
                acc.x += w[k] * bf2f(dv.x);
                acc.y += w[k] * bf2f(dv.y);
                acc.z += w[k] * bf2f(dv.z);
                acc.w += w[k] * bf2f(dv.w);
            }
        }
        yrow[h4] = acc;
    }
}

extern "C" void kernel_launch(void* const* d_in, const int* in_sizes, int n_in,
                              void* d_out, int out_size, void* d_ws, size_t ws_size,
                              hipStream_t stream) {
    const float* x       = (const float*)d_in[0];
    const float* gw      = (const float*)d_in[1];
    const float* w_gate  = (const float*)d_in[2];
    const float* w_up    = (const float*)d_in[3];
    const float* w_down  = (const float*)d_in[4];
    const float* sh_gate = (const float*)d_in[5];
    const float* sh_up   = (const float*)d_in[6];
    const float* sh_down = (const float*)d_in[7];
    float* y = (float*)d_out;

    char* wsb = (char*)d_ws;
    int*   cnt      = (int*)(wsb + 0);                       // 64 ints
    int*   tok_of   = (int*)(wsb + 512);                     // 64*512 ints
    int*   slot_enc = (int*)(wsb + 512 + 131072);            // 2048*6 ints
    float* tw       = (float*)(wsb + 512 + 131072 + 49152);  // 2048*6 floats
    u16*   act      = (u16*)(wsb + 230144);                  // 64*512*1408 bf16
    u16*   actsh    = (u16*)(wsb + 230144 + 92274688);       // 2048*2816 bf16
    u16*   dbuf     = (u16*)(wsb + 230144 + 92274688 + 11534336); // 64*512*2048 bf16

    init_cnt<<<1, 64, 0, stream>>>(cnt);
    gate_topk<<<NTOK, 64, 0, stream>>>(x, gw, cnt, tok_of, slot_enc, tw);
    dual_gemm<true><<<dim3(FDIM / 64, 2, NE), 256, 0, stream>>>(
        x, tok_of, cnt, w_gate, w_up, act, FDIM);
    dual_gemm<false><<<dim3(FSH / 64, NTOK / 256, 1), 256, 0, stream>>>(
        x, nullptr, nullptr, sh_gate, sh_up, actsh, FSH);
    down_gemm<true><<<dim3(H / 128, 2, NE), 256, 0, stream>>>(
        act, w_down, (void*)dbuf, cnt, FDIM);
    down_gemm<false><<<dim3(H / 128, NTOK / 256, 1), 256, 0, stream>>>(
        actsh, sh_down, (void*)y, nullptr, FSH);
    combine<<<NTOK, 256, 0, stream>>>(y, dbuf, slot_enc, tw);
}

// Round 2
// 936.981 us; speedup vs baseline: 2.9048x; 2.9048x over previous
//
#include <hip/hip_runtime.h>
#include <hip/hip_bf16.h>

#define H 2048
#define FDIM 1408
#define NE 64
#define CAP 512
#define NTOK 2048
#define FSH 2816

typedef float  f32x4  __attribute__((ext_vector_type(4)));
typedef short  s16x8  __attribute__((ext_vector_type(8)));
typedef unsigned short u16;
typedef u16    u16x4v __attribute__((ext_vector_type(4)));

__device__ __forceinline__ u16 f2bf(float f) {
    union { float f; unsigned u; } v; v.f = f;
    unsigned u = v.u;
    u += 0x7fffu + ((u >> 16) & 1u);
    return (u16)(u >> 16);
}
__device__ __forceinline__ float bf2f(u16 b) {
    union { unsigned u; float f; } v; v.u = ((unsigned)b) << 16;
    return v.f;
}
// element-granular XOR swizzle (multiples of 8 elems = 16B) within 64-elem rows
__device__ __forceinline__ int swze(int row) {
    return (((row & 7) ^ ((row >> 3) & 7)) << 3);
}
__device__ __forceinline__ void wr4(u16* dst, float a, float b, float c, float d) {
    u16x4v v; v[0] = f2bf(a); v[1] = f2bf(b); v[2] = f2bf(c); v[3] = f2bf(d);
    *(u16x4v*)dst = v;
}

// ---------------- x fp32 -> bf16 once ----------------
__global__ __launch_bounds__(256) void xcvt(const float* __restrict__ x, u16* __restrict__ xb) {
    int i = blockIdx.x * 256 + threadIdx.x;          // one 8-elem chunk per thread
    const float4 a = ((const float4*)x)[2 * i];
    const float4 b = ((const float4*)x)[2 * i + 1];
    u16 v[8] = { f2bf(a.x), f2bf(a.y), f2bf(a.z), f2bf(a.w),
                 f2bf(b.x), f2bf(b.y), f2bf(b.z), f2bf(b.w) };
    *(s16x8*)(xb + (size_t)i * 8) = *(s16x8*)v;
}

// ---------------- init: zero per-expert counters ----------------
__global__ void init_cnt(int* __restrict__ c) { c[threadIdx.x] = 0; }

// ---------------- gate: logits -> softmax -> top6 -> slot assign ----------------
__global__ __launch_bounds__(64) void gate_topk(
    const float* __restrict__ xg, const float* __restrict__ gw,
    int* __restrict__ cnt, int* __restrict__ tok_of,
    int* __restrict__ slot_enc, float* __restrict__ tw)
{
    const int t = blockIdx.x;
    const int lane = threadIdx.x;              // 64 threads = 1 wave
    __shared__ float4 xs[512];
    const float4* xr = (const float4*)(xg + (size_t)t * H);
    #pragma unroll
    for (int i = 0; i < 8; ++i) xs[i * 64 + lane] = xr[i * 64 + lane];
    __syncthreads();

    const float4* gr = (const float4*)(gw + (size_t)lane * H);
    float acc = 0.f;
    #pragma unroll 4
    for (int i = 0; i < 512; ++i) {
        float4 a = xs[i], b = gr[i];
        acc += a.x * b.x + a.y * b.y + a.z * b.z + a.w * b.w;
    }
    float m = acc;
    #pragma unroll
    for (int off = 32; off; off >>= 1) m = fmaxf(m, __shfl_xor(m, off));
    float p = __expf(acc - m);
    float s = p;
    #pragma unroll
    for (int off = 32; off; off >>= 1) s += __shfl_xor(s, off);
    p = p / s;

    float myw = 0.f; int mye = 0;
    float v = p;
    for (int k = 0; k < 6; ++k) {
        float bv = v; int bi = lane;
        #pragma unroll
        for (int off = 32; off; off >>= 1) {
            float ov = __shfl_xor(bv, off);
            int   oi = __shfl_xor(bi, off);
            if (ov > bv || (ov == bv && oi < bi)) { bv = ov; bi = oi; }
        }
        if (lane == k)  { myw = bv; mye = bi; }
        if (lane == bi) v = -1.f;
    }
    if (lane < 6) {
        int slot = atomicAdd(&cnt[mye], 1);
        int enc = -1;
        if (slot < CAP) { tok_of[mye * CAP + slot] = t; enc = mye * CAP + slot; }
        slot_enc[t * 6 + lane] = enc;
        tw[t * 6 + lane] = myw;               // SCALE == 1.0
    }
}

// ---------------- fused gate+up grouped GEMM + SiLU (2-phase reg-prefetch) ----------------
// BM=256, BN=32 (per mat), BK=64. ROUTED: B transpose-staged from [H][F].
// !ROUTED: B direct-staged from [FSH][H]. act written bf16 with swizzle baked.
template<bool ROUTED>
__global__ __launch_bounds__(256) void dual_gemm(
    const u16* __restrict__ xbf, const int* __restrict__ tok_of,
    const int* __restrict__ cnt_arr, const float* __restrict__ wg,
    const float* __restrict__ wu, u16* __restrict__ act, int Fd)
{
    __shared__ u16 As[256 * 64];
    __shared__ u16 Bgs[32 * 64];
    __shared__ u16 Bus[32 * 64];

    const int e = blockIdx.z;
    int cnt;
    if constexpr (ROUTED) { cnt = cnt_arr[e]; cnt = cnt < CAP ? cnt : CAP; }
    else cnt = NTOK;
    const int m0 = blockIdx.y * 256;
    if (m0 >= cnt) return;
    const int f0 = blockIdx.x * 32;

    const float* wg_e = wg;
    const float* wu_e = wu;
    u16* act_e = act;
    const int* tok = nullptr;
    if constexpr (ROUTED) {
        wg_e += (size_t)e * H * Fd;
        wu_e += (size_t)e * H * Fd;
        act_e += (size_t)e * CAP * Fd;
        tok = tok_of + e * CAP;
    }

    const int tid = threadIdx.x;
    const int lane = tid & 63;
    const int wv = tid >> 6;

    // ---- per-thread fixed staging geometry ----
    // A: 8 chunks of 8 bf16; rows it*32 + (tid>>3), chunk col c = tid&7
    const int ac = tid & 7;
    const u16* arow[8];
    int arl[8];
    #pragma unroll
    for (int it = 0; it < 8; ++it) {
        int row = it * 32 + (tid >> 3);
        arl[it] = row;
        int srow = m0 + row;
        int tkn;
        if constexpr (ROUTED) tkn = (srow < cnt) ? tok[srow] : 0;
        else tkn = srow;
        arow[it] = xbf + (size_t)tkn * H;
    }
    // B (ROUTED): one 4x4 transpose block per thread; tid<128 gate, else up
    const int bb = tid & 127;
    const int bn4 = bb & 7;          // 8 * 4 = 32 cols
    const int bkb = bb >> 3;         // 16 * 4 = 64 k
    const float* bsrcR = ((tid < 128) ? wg_e : wu_e) + (size_t)f0 + bn4 * 4 + (size_t)bkb * 4 * Fd;
    // B (!ROUTED): direct rows; tid<128 gate, else up; row=bb>>2, 4 chunks at (bb&3)*4+q
    const int dr = bb >> 2;
    const int dc = (bb & 3) * 4;
    const float* bsrcD = ((tid < 128) ? wg_e : wu_e) + (size_t)(f0 + dr) * H + dc * 4;

    f32x4 accg[4][2], accu[4][2];
    const f32x4 zero4 = {0.f, 0.f, 0.f, 0.f};
    #pragma unroll
    for (int i = 0; i < 4; ++i)
        #pragma unroll
        for (int j = 0; j < 2; ++j) { accg[i][j] = zero4; accu[i][j] = zero4; }

    s16x8 aR[8];
    float4 bR[4];

    // ---- prologue: load tile 0 ----
    #pragma unroll
    for (int it = 0; it < 8; ++it) aR[it] = *(const s16x8*)(arow[it] + ac * 8);
    if constexpr (ROUTED) {
        #pragma unroll
        for (int r = 0; r < 4; ++r) bR[r] = *(const float4*)(bsrcR + (size_t)r * Fd);
    } else {
        #pragma unroll
        for (int q = 0; q < 4; ++q) bR[q] = *(const float4*)(bsrcD + q * 4);
    }

    for (int kt = 0; kt < H / 64; ++kt) {
        // ---- write staged regs -> LDS ----
        #pragma unroll
        for (int it = 0; it < 8; ++it)
            *(s16x8*)&As[arl[it] * 64 + ((ac * 8) ^ swze(arl[it]))] = aR[it];
        u16* Bdst = (tid < 128) ? Bgs : Bus;
        if constexpr (ROUTED) {
            #pragma unroll
            for (int j = 0; j < 4; ++j) {
                int rr = bn4 * 4 + j;
                wr4(&Bdst[rr * 64 + ((bkb * 4) ^ swze(rr))], bR[0][j], bR[1][j], bR[2][j], bR[3][j]);
            }
        } else {
            #pragma unroll
            for (int q = 0; q < 4; ++q)
                wr4(&Bdst[dr * 64 + (((dc + q) * 4) ^ swze(dr))], bR[q].x, bR[q].y, bR[q].z, bR[q].w);
        }
        __syncthreads();

        // ---- issue next tile's global loads (overlap with MFMA below) ----
        if (kt + 1 < H / 64) {
            const int ko = (kt + 1) * 64;
            #pragma unroll
            for (int it = 0; it < 8; ++it) aR[it] = *(const s16x8*)(arow[it] + ko + ac * 8);
            if constexpr (ROUTED) {
                #pragma unroll
                for (int r = 0; r < 4; ++r) bR[r] = *(const float4*)(bsrcR + (size_t)(ko + r) * Fd);
            } else {
                #pragma unroll
                for (int q = 0; q < 4; ++q) bR[q] = *(const float4*)(bsrcD + ko + q * 4);
            }
        }

        // ---- compute ----
        __builtin_amdgcn_s_setprio(1);
        #pragma unroll
        for (int kk = 0; kk < 2; ++kk) {
            int ko = kk * 32 + (lane >> 4) * 8;
            s16x8 a[4], bg[2], bu[2];
            #pragma unroll
            for (int mi = 0; mi < 4; ++mi) {
                int r = wv * 64 + mi * 16 + (lane & 15);
                a[mi] = *(const s16x8*)&As[r * 64 + (ko ^ swze(r))];
            }
            #pragma unroll
            for (int ni = 0; ni < 2; ++ni) {
                int r = ni * 16 + (lane & 15);
                bg[ni] = *(const s16x8*)&Bgs[r * 64 + (ko ^ swze(r))];
                bu[ni] = *(const s16x8*)&Bus[r * 64 + (ko ^ swze(r))];
            }
            #pragma unroll
            for (int mi = 0; mi < 4; ++mi)
                #pragma unroll
                for (int ni = 0; ni < 2; ++ni) {
                    accg[mi][ni] = __builtin_amdgcn_mfma_f32_16x16x32_bf16(a[mi], bg[ni], accg[mi][ni], 0, 0, 0);
                    accu[mi][ni] = __builtin_amdgcn_mfma_f32_16x16x32_bf16(a[mi], bu[ni], accu[mi][ni], 0, 0, 0);
                }
        }
        __builtin_amdgcn_s_setprio(0);
        __syncthreads();
    }

    // ---- epilogue: silu(g)*u -> bf16 act (swizzle baked into f) ----
    #pragma unroll
    for (int mi = 0; mi < 4; ++mi)
        #pragma unroll
        for (int ni = 0; ni < 2; ++ni)
            #pragma unroll
            for (int r = 0; r < 4; ++r) {
                int srow = m0 + wv * 64 + mi * 16 + (lane >> 4) * 4 + r;
                if (srow < cnt) {
                    int fc = f0 + ni * 16 + (lane & 15);
                    float g = accg[mi][ni][r], u = accu[mi][ni][r];
                    float aa = (g / (1.f + __expf(-g))) * u;
                    int fs = (fc & ~63) | ((fc & 63) ^ swze(srow));
                    act_e[(size_t)srow * Fd + fs] = f2bf(aa);
                }
            }
}

// ---------------- down-proj grouped GEMM (2-phase reg-prefetch) ----------------
// BM=256, BN=64, BK=64. ROUTED: A=act bf16 (pre-swizzled), B=w_down [F][H] transposed, out=dbuf bf16.
// !ROUTED: A=actsh, B=sh_down [H][FSH] direct, out=y fp32.
template<bool ROUTED>
__global__ __launch_bounds__(256) void down_gemm(
    const u16* __restrict__ actA, const float* __restrict__ wdn,
    void* __restrict__ outp, const int* __restrict__ cnt_arr, int Kd)
{
    __shared__ u16 As[256 * 64];
    __shared__ u16 Bs[64 * 64];

    const int e = blockIdx.z;
    int cnt;
    if constexpr (ROUTED) { cnt = cnt_arr[e]; cnt = cnt < CAP ? cnt : CAP; }
    else cnt = NTOK;
    const int m0 = blockIdx.y * 256;
    if (m0 >= cnt) return;
    const int n0 = blockIdx.x * 64;

    const u16* A_e = actA;
    const float* B_e = wdn;
    if constexpr (ROUTED) {
        A_e += (size_t)e * CAP * Kd;
        B_e += (size_t)e * Kd * H;
    }

    const int tid = threadIdx.x, lane = tid & 63, wv = tid >> 6;
    const int NT = Kd / 64;

    // A: 8 chunks of 8 bf16; rows it*32 + (tid>>3)
    const int ac = tid & 7;
    int arl[8];
    const u16* arow[8];
    #pragma unroll
    for (int it = 0; it < 8; ++it) {
        int row = it * 32 + (tid >> 3);
        arl[it] = row;
        arow[it] = A_e + (size_t)(m0 + row) * Kd;
    }
    // B (ROUTED): one 4x4 block per thread: n4 = tid&15 (64 cols), kb = tid>>4 (64 k)
    const int bn4 = tid & 15;
    const int bkb = tid >> 4;
    const float* bsrcR = B_e + (size_t)n0 + bn4 * 4 + (size_t)bkb * 4 * H;
    // B (!ROUTED): direct rows: row = tid>>2 (64 rows), chunks (tid&3)*4+q
    const int dr = tid >> 2;
    const int dc = (tid & 3) * 4;
    const float* bsrcD = B_e + (size_t)(n0 + dr) * FSH + dc * 4;

    f32x4 acc[4][4];
    const f32x4 zero4 = {0.f, 0.f, 0.f, 0.f};
    #pragma unroll
    for (int i = 0; i < 4; ++i)
        #pragma unroll
        for (int j = 0; j < 4; ++j) acc[i][j] = zero4;

    s16x8 aR[8];
    float4 bR[4];

    #pragma unroll
    for (int it = 0; it < 8; ++it) aR[it] = *(const s16x8*)(arow[it] + ac * 8);
    if constexpr (ROUTED) {
        #pragma unroll
        for (int r = 0; r < 4; ++r) bR[r] = *(const float4*)(bsrcR + (size_t)r * H);
    } else {
        #pragma unroll
        for (int q = 0; q < 4; ++q) bR[q] = *(const float4*)(bsrcD + q * 4);
    }

    for (int kt = 0; kt < NT; ++kt) {
        #pragma unroll
        for (int it = 0; it < 8; ++it)
            *(s16x8*)&As[arl[it] * 64 + (ac * 8)] = aR[it];   // pre-swizzled rows: linear copy
        if constexpr (ROUTED) {
            #pragma unroll
            for (int j = 0; j < 4; ++j) {
                int rr = bn4 * 4 + j;
                wr4(&Bs[rr * 64 + ((bkb * 4) ^ swze(rr))], bR[0][j], bR[1][j], bR[2][j], bR[3][j]);
            }
        } else {
            #pragma unroll
            for (int q = 0; q < 4; ++q)
                wr4(&Bs[dr * 64 + (((dc + q) * 4) ^ swze(dr))], bR[q].x, bR[q].y, bR[q].z, bR[q].w);
        }
        __syncthreads();

        if (kt + 1 < NT) {
            const int ko = (kt + 1) * 64;
            #pragma unroll
            for (int it = 0; it < 8; ++it) aR[it] = *(const s16x8*)(arow[it] + ko + ac * 8);
            if constexpr (ROUTED) {
                #pragma unroll
                for (int r = 0; r < 4; ++r) bR[r] = *(const float4*)(bsrcR + (size_t)(ko + r) * H);
            } else {
                #pragma unroll
                for (int q = 0; q < 4; ++q) bR[q] = *(const float4*)(bsrcD + ko + q * 4);
            }
        }

        __builtin_amdgcn_s_setprio(1);
        #pragma unroll
        for (int kk = 0; kk < 2; ++kk) {
            int ko = kk * 32 + (lane >> 4) * 8;
            s16x8 a[4], b[4];
            #pragma unroll
            for (int mi = 0; mi < 4; ++mi) {
                int r = wv * 64 + mi * 16 + (lane & 15);
                a[mi] = *(const s16x8*)&As[r * 64 + (ko ^ swze(r))];
            }
            #pragma unroll
            for (int ni = 0; ni < 4; ++ni) {
                int r = ni * 16 + (lane & 15);
                b[ni] = *(const s16x8*)&Bs[r * 64 + (ko ^ swze(r))];
            }
            #pragma unroll
            for (int mi = 0; mi < 4; ++mi)
                #pragma unroll
                for (int ni = 0; ni < 4; ++ni)
                    acc[mi][ni] = __builtin_amdgcn_mfma_f32_16x16x32_bf16(a[mi], b[ni], acc[mi][ni], 0, 0, 0);
        }
        __builtin_amdgcn_s_setprio(0);
        __syncthreads();
    }

    #pragma unroll
    for (int mi = 0; mi < 4; ++mi)
        #pragma unroll
        for (int ni = 0; ni < 4; ++ni)
            #pragma unroll
            for (int r = 0; r < 4; ++r) {
                int srow = m0 + wv * 64 + mi * 16 + (lane >> 4) * 4 + r;
                if (srow < cnt) {
                    int col = n0 + ni * 16 + (lane & 15);
                    float vv = acc[mi][ni][r];
                    if constexpr (ROUTED)
                        ((u16*)outp)[(size_t)e * CAP * H + (size_t)srow * H + col] = f2bf(vv);
                    else
                        ((float*)outp)[(size_t)srow * H + col] = vv;
                }
            }
}

// ---------------- combine: y += sum_k w_k * d[enc_k] ----------------
__global__ __launch_bounds__(256) void combine(
    float* __restrict__ y, const u16* __restrict__ d,
    const int* __restrict__ slot_enc, const float* __restrict__ tw)
{
    const int t = blockIdx.x, tid = threadIdx.x;
    int enc[6]; float w[6];
    #pragma unroll
    for (int k = 0; k < 6; ++k) {
        enc[k] = slot_enc[t * 6 + k];
        w[k] = tw[t * 6 + k];
    }
    float4* yrow = (float4*)(y + (size_t)t * H);
    #pragma unroll
    for (int it = 0; it < 2; ++it) {
        int h4 = it * 256 + tid;
        float4 acc = yrow[h4];
        #pragma unroll
        for (int k = 0; k < 6; ++k) {
            if (enc[k] >= 0) {
                ushort4 dv = ((const ushort4*)(d + (size_t)enc[k] * H))[h4];
                acc.x += w[k] * bf2f(dv.x);
                acc.y += w[k] * bf2f(dv.y);
                acc.z += w[k] * bf2f(dv.z);
                acc.w += w[k] * bf2f(dv.w);
            }
        }
        yrow[h4] = acc;
    }
}

extern "C" void kernel_launch(void* const* d_in, const int* in_sizes, int n_in,
                              void* d_out, int out_size, void* d_ws, size_t ws_size,
                              hipStream_t stream) {
    const float* x       = (const float*)d_in[0];
    const float* gw      = (const float*)d_in[1];
    const float* w_gate  = (const float*)d_in[2];
    const float* w_up    = (const float*)d_in[3];
    const float* w_down  = (const float*)d_in[4];
    const float* sh_gate = (const float*)d_in[5];
    const float* sh_up   = (const float*)d_in[6];
    const float* sh_down = (const float*)d_in[7];
    float* y = (float*)d_out;

    char* wsb = (char*)d_ws;
    int*   cnt      = (int*)(wsb + 0);                       // 64 ints
    int*   tok_of   = (int*)(wsb + 512);                     // 64*512 ints
    int*   slot_enc = (int*)(wsb + 512 + 131072);            // 2048*6 ints
    float* tw       = (float*)(wsb + 512 + 131072 + 49152);  // 2048*6 floats
    u16*   act      = (u16*)(wsb + 230144);                  // 64*512*1408 bf16
    u16*   actsh    = (u16*)(wsb + 230144 + 92274688);       // 2048*2816 bf16
    u16*   dbuf     = (u16*)(wsb + 230144 + 92274688 + 11534336); // 64*512*2048 bf16
    u16*   xbf      = dbuf;  // alias: xbf (8MB) only live before down_gemm writes dbuf

    init_cnt<<<1, 64, 0, stream>>>(cnt);
    xcvt<<<NTOK * H / 8 / 256, 256, 0, stream>>>(x, xbf);
    gate_topk<<<NTOK, 64, 0, stream>>>(x, gw, cnt, tok_of, slot_enc, tw);
    dual_gemm<true><<<dim3(FDIM / 32, 2, NE), 256, 0, stream>>>(
        xbf, tok_of, cnt, w_gate, w_up, act, FDIM);
    dual_gemm<false><<<dim3(FSH / 32, NTOK / 256, 1), 256, 0, stream>>>(
        xbf, nullptr, nullptr, sh_gate, sh_up, actsh, FSH);
    down_gemm<true><<<dim3(H / 64, 2, NE), 256, 0, stream>>>(
        act, w_down, (void*)dbuf, cnt, FDIM);
    down_gemm<false><<<dim3(H / 64, NTOK / 256, 1), 256, 0, stream>>>(
        actsh, sh_down, (void*)y, nullptr, FSH);
    combine<<<NTOK, 256, 0, stream>>>(y, dbuf, slot_enc, tw);
}